// Round 1
// baseline (1759.605 us; speedup 1.0000x reference)
//
#include <hip/hip_runtime.h>

// Problem constants (from reference): C=64,K=7,S=2,RATIO=2,GC=16
namespace {
constexpr int kB    = 8;
constexpr int kC    = 64;
constexpr int kH    = 64, kW = 64;
constexpr int kK    = 7,  kKK = 49;
constexpr int kGC   = 16, kG  = 4;
constexpr int kHo   = 32, kWo = 32;
constexpr int kNP   = kB * kHo * kWo;   // 8192 spatial positions
constexpr int kC1In = 1092;             // G*(2*K*GC + K*K)
constexpr int kC1Out= 313;              // G*NN*KK/10
constexpr int kC2Out= 3136;             // G*NN*KK
constexpr int kNN   = 16;
constexpr int kC1P  = 320;              // padded C1Out (aligned float4 chunks)
constexpr int kHRow = 324;              // LDS row stride (floats), 16B aligned
}

__device__ __forceinline__ float xval(const float* __restrict__ xb, int ch, int yy, int xx) {
    // zero padding: out-of-bounds patch entries are exactly 0.0f (matches jnp.pad)
    if ((unsigned)yy < 64u && (unsigned)xx < 64u)
        return xb[((size_t)ch << 12) + (yy << 6) + xx];
    return 0.f;
}

// ---------------- K0: pad w2 [3136][313] -> [3136][320] (zero-filled) -------
__global__ void k_padw2(const float* __restrict__ w2, float* __restrict__ w2p) {
    int idx = blockIdx.x * 256 + threadIdx.x;
    if (idx >= kC2Out * kC1P) return;
    int r = idx / kC1P, c = idx - r * kC1P;
    w2p[idx] = (c < kC1Out) ? w2[(size_t)r * kC1Out + c] : 0.f;
}

// ---------------- K1: feat[p][c], p = (b*32+i)*32+j ------------------------
__global__ void k_feat(const float* __restrict__ x, float* __restrict__ feat) {
    int c = blockIdx.x * 256 + threadIdx.x;
    int p = blockIdx.y;
    if (c >= kC1In) return;
    int b = p >> 10, i = (p >> 5) & 31, j = p & 31;
    int y0 = 2 * i - 3, x0 = 2 * j - 3;
    const float* xb = x + (size_t)b * kC * kH * kW;
    float m = -INFINITY;
    if (c < 196) {                       // x1: max over group channels
        int g = c / 49, r = c % 49, a = r / 7, bk = r % 7;
        int yy = y0 + a, xx = x0 + bk;
        #pragma unroll
        for (int ch = 0; ch < 16; ++ch)
            m = fmaxf(m, xval(xb, g * 16 + ch, yy, xx));
    } else if (c < 644) {                // x2: max over kernel-row a
        int c2 = c - 196;
        int g = c2 / 112, r = c2 % 112, ch = r / 7, bk = r % 7;
        int xx = x0 + bk, ca = g * 16 + ch;
        #pragma unroll
        for (int a = 0; a < 7; ++a)
            m = fmaxf(m, xval(xb, ca, y0 + a, xx));
    } else {                             // x3: max over kernel-col bk
        int c3 = c - 644;
        int g = c3 / 112, r = c3 % 112, ch = r / 7, a = r % 7;
        int yy = y0 + a, ca = g * 16 + ch;
        #pragma unroll
        for (int bk = 0; bk < 7; ++bk)
            m = fmaxf(m, xval(xb, ca, yy, x0 + bk));
    }
    feat[(size_t)p * kC1In + c] = m;
}

// ---------------- K2: h = feat * w1^T, fused BN partial sums ---------------
// A: feat [8192][1092]  B: w1 [313][1092]  C: h [8192][313]
__global__ __launch_bounds__(256) void k_gemm1(const float* __restrict__ feat,
        const float* __restrict__ w1, float* __restrict__ h,
        float* __restrict__ sum_, float* __restrict__ sumsq_) {
    __shared__ float As[16][65];
    __shared__ float Bs[16][65];
    __shared__ float lsum[64], lsq[64];
    int tid = threadIdx.x;
    int tx = tid & 15, ty = tid >> 4;
    int row0 = blockIdx.y * 64, col0 = blockIdx.x * 64;
    float acc[4][4] = {};
    for (int k0 = 0; k0 < kC1In; k0 += 16) {
        #pragma unroll
        for (int l = 0; l < 4; ++l) {
            int idx = tid + l * 256;          // 0..1023
            int m = idx >> 4, k = idx & 15;
            bool kin = (k0 + k < kC1In);
            As[k][m] = kin ? feat[(size_t)(row0 + m) * kC1In + k0 + k] : 0.f;
            float bv = 0.f;
            if (kin && (col0 + m < kC1Out))
                bv = w1[(size_t)(col0 + m) * kC1In + k0 + k];
            Bs[k][m] = bv;
        }
        __syncthreads();
        #pragma unroll
        for (int k = 0; k < 16; ++k) {
            float a[4], bvv[4];
            #pragma unroll
            for (int i = 0; i < 4; ++i) a[i] = As[k][ty + 16 * i];
            #pragma unroll
            for (int j = 0; j < 4; ++j) bvv[j] = Bs[k][tx + 16 * j];
            #pragma unroll
            for (int i = 0; i < 4; ++i)
                #pragma unroll
                for (int j = 0; j < 4; ++j)
                    acc[i][j] += a[i] * bvv[j];
        }
        __syncthreads();
    }
    if (tid < 64) { lsum[tid] = 0.f; lsq[tid] = 0.f; }
    __syncthreads();
    #pragma unroll
    for (int i = 0; i < 4; ++i) {
        int m = ty + 16 * i;
        #pragma unroll
        for (int j = 0; j < 4; ++j) {
            int n = tx + 16 * j;
            if (col0 + n < kC1Out) {
                float v = acc[i][j];
                h[(size_t)(row0 + m) * kC1Out + col0 + n] = v;
                atomicAdd(&lsum[n], v);
                atomicAdd(&lsq[n], v * v);
            }
        }
    }
    __syncthreads();
    if (tid < 64 && col0 + tid < kC1Out) {
        atomicAdd(&sum_[col0 + tid], lsum[tid]);
        atomicAdd(&sumsq_[col0 + tid], lsq[tid]);
    }
}

// ---------------- K3: finalize BN scale/shift ------------------------------
__global__ void k_finalize(const float* __restrict__ sum_, const float* __restrict__ sumsq_,
                           const float* __restrict__ gamma, const float* __restrict__ beta,
                           float* __restrict__ scale, float* __restrict__ shift) {
    int o = blockIdx.x * 256 + threadIdx.x;
    if (o >= kC1Out) return;
    float mu  = sum_[o]   * (1.f / kNP);
    float var = sumsq_[o] * (1.f / kNP) - mu * mu;
    float sc  = gamma[o] * rsqrtf(var + 1e-5f);
    scale[o] = sc;
    shift[o] = beta[o] - mu * sc;
}

// ---------------- K4: BN+ReLU -> GEMM2 -> softmax(49) -> weighted patch sum
// One block = 16 consecutive positions (same b,i; j0..j0+15). 256 threads.
// Thread t: pos = t&15, handles gn = t>>4 + 16*it for it in 0..3.
__global__ __launch_bounds__(256) void k_second(const float* __restrict__ h,
        const float* __restrict__ scale, const float* __restrict__ shift,
        const float* __restrict__ w2p, const float* __restrict__ b2,
        const float* __restrict__ x, float* __restrict__ out) {
    __shared__ float hh2[16 * kHRow];   // [pos][c] padded, 20.7 KB
    int tid = threadIdx.x;
    int p0 = blockIdx.x * 16;
    // phase 1: BN + ReLU into LDS (transposed per-position rows)
    for (int e = tid; e < 16 * kHRow; e += 256) {
        int pos = e / kHRow;
        int c = e - pos * kHRow;
        float v = 0.f;
        if (c < kC1Out) {
            float hv = h[(size_t)(p0 + pos) * kC1Out + c];
            v = fmaxf(hv * scale[c] + shift[c], 0.f);
        }
        hh2[e] = v;
    }
    __syncthreads();

    int pos = tid & 15;
    int p = p0 + pos;
    int b = p >> 10, i = (p >> 5) & 31, j = p & 31;
    int y0 = 2 * i - 3, x0c = 2 * j - 3;
    const float* xb = x + (size_t)b * kC * kH * kW;
    float* outb = out + (size_t)b * kC * 128 * 128;
    const float4* hp = (const float4*)(hh2 + pos * kHRow);

    for (int it = 0; it < 4; ++it) {
        int gn = (tid >> 4) + (it << 4);
        int g = gn >> 4, n = gn & 15;
        int rowbase = g * 784 + n;           // w2 row = rowbase + k*16
        float v[49];
        #pragma unroll
        for (int k = 0; k < 49; ++k) v[k] = b2[rowbase + (k << 4)];
        const float* wbase = w2p + (size_t)rowbase * kC1P;
        // phase 2: h2[k] = b2 + sum_c w2[row_k][c] * hh(pos,c)
        for (int c0 = 0; c0 < kC1P; c0 += 8) {
            float4 h0 = hp[(c0 >> 2)];
            float4 h1 = hp[(c0 >> 2) + 1];
            #pragma unroll
            for (int k = 0; k < 49; ++k) {
                const float4* wp = (const float4*)(wbase + (size_t)(k << 4) * kC1P + c0);
                float4 w0 = wp[0], w1v = wp[1];
                v[k] += w0.x * h0.x + w0.y * h0.y + w0.z * h0.z + w0.w * h0.w
                      + w1v.x * h1.x + w1v.y * h1.y + w1v.z * h1.z + w1v.w * h1.w;
            }
        }
        // phase 3: softmax over k (fold in the /49)
        float m = v[0];
        #pragma unroll
        for (int k = 1; k < 49; ++k) m = fmaxf(m, v[k]);
        float s = 0.f;
        #pragma unroll
        for (int k = 0; k < 49; ++k) { v[k] = __expf(v[k] - m); s += v[k]; }
        float inv = 1.f / (s * 49.f);
        #pragma unroll
        for (int k = 0; k < 49; ++k) v[k] *= inv;
        // phase 4: out[g,c16,n] = sum_k patch(g,c16,k) * v[k]
        int n1 = n >> 2, n2 = n & 3;
        int orow = i * 4 + n1, ocol = j * 4 + n2;
        for (int c16 = 0; c16 < 16; ++c16) {
            float o = 0.f;
            const float* xc = xb + ((size_t)(g * 16 + c16) << 12);
            #pragma unroll
            for (int a = 0; a < 7; ++a) {
                int yy = y0 + a;
                if ((unsigned)yy < 64u) {
                    #pragma unroll
                    for (int bk = 0; bk < 7; ++bk) {
                        int xx = x0c + bk;
                        if ((unsigned)xx < 64u)
                            o += xc[(yy << 6) + xx] * v[a * 7 + bk];
                    }
                }
            }
            outb[((size_t)(g * 16 + c16) * 128 + orow) * 128 + ocol] = o;
        }
    }
}

extern "C" void kernel_launch(void* const* d_in, const int* in_sizes, int n_in,
                              void* d_out, int out_size, void* d_ws, size_t ws_size,
                              hipStream_t stream) {
    const float* x     = (const float*)d_in[0];
    const float* w1    = (const float*)d_in[1];
    const float* gamma = (const float*)d_in[2];
    const float* beta  = (const float*)d_in[3];
    const float* w2    = (const float*)d_in[4];
    const float* b2    = (const float*)d_in[5];
    float* out = (float*)d_out;

    // workspace layout (floats); total ~50.1 MB
    float* ws     = (float*)d_ws;
    float* feat   = ws;                                   // 8192*1092
    float* h      = feat + (size_t)kNP * kC1In;           // 8192*313
    float* w2p    = h + (size_t)kNP * kC1Out;             // 3136*320
    float* sum_   = w2p + (size_t)kC2Out * kC1P;          // 320
    float* sumsq_ = sum_ + 320;                           // 320
    float* scale  = sumsq_ + 320;                         // 320
    float* shift  = scale + 320;                          // 320

    hipMemsetAsync(sum_, 0, 2 * 320 * sizeof(float), stream);
    k_padw2<<<(kC2Out * kC1P + 255) / 256, 256, 0, stream>>>(w2, w2p);
    k_feat<<<dim3((kC1In + 255) / 256, kNP), 256, 0, stream>>>(x, feat);
    k_gemm1<<<dim3(5, kNP / 64), 256, 0, stream>>>(feat, w1, h, sum_, sumsq_);
    k_finalize<<<2, 256, 0, stream>>>(sum_, sumsq_, gamma, beta, scale, shift);
    k_second<<<kNP / 16, 256, 0, stream>>>(h, scale, shift, w2p, b2, x, out);
}

// Round 2
// 475.951 us; speedup vs baseline: 3.6970x; 3.6970x over previous
//
#include <hip/hip_runtime.h>

namespace {
constexpr int kB    = 8;
constexpr int kC    = 64;
constexpr int kH    = 64, kW = 64;
constexpr int kK    = 7,  kKK = 49;
constexpr int kGC   = 16, kG  = 4;
constexpr int kHo   = 32, kWo = 32;
constexpr int kNP   = kB * kHo * kWo;   // 8192 positions
constexpr int kC1In = 1092;
constexpr int kC1Out= 313;
constexpr int kC2Out= 3136;
constexpr int kC1P  = 320;              // padded C1Out
constexpr int kWtStride = 788;          // LDS h2/wt row stride (floats)
}

typedef __attribute__((ext_vector_type(8))) short bf16x8;
typedef __attribute__((ext_vector_type(4))) float f32x4;

__device__ __forceinline__ unsigned short f2bf(float f) {
    unsigned u = __float_as_uint(f);
    unsigned r = (u + 0x7fffu + ((u >> 16) & 1u)) >> 16;   // RNE
    return (unsigned short)r;
}
__device__ __forceinline__ float bf2f(unsigned short h) {
    return __uint_as_float(((unsigned)h) << 16);
}

__device__ __forceinline__ float xval(const float* __restrict__ xb, int ch, int yy, int xx) {
    if ((unsigned)yy < 64u && (unsigned)xx < 64u)
        return xb[((size_t)ch << 12) + (yy << 6) + xx];
    return 0.f;
}

// ---------------- K0: split w2 into frag-ready bf16 hi/lo -------------------
// layout: w2t[((g*49 + k)*10 + t)*64 + lane] = 8 bf16; value[e] =
//   w2[(g*784 + k*16 + (lane&15)) * 313 + t*32 + (lane>>4)*8 + e]  (0 if c>=313)
__global__ void k_w2split(const float* __restrict__ w2,
                          bf16x8* __restrict__ w2t_hi, bf16x8* __restrict__ w2t_lo) {
    int idx = blockIdx.x * 256 + threadIdx.x;   // 4*49*10*64 = 125440
    int lane = idx & 63;
    int t = (idx >> 6) % 10;
    int k = (idx / 640) % 49;
    int g = idx / 31360;
    int n = lane & 15, c0 = t * 32 + ((lane >> 4) << 3);
    int row = g * 784 + k * 16 + n;
    bf16x8 hi, lo;
    #pragma unroll
    for (int e = 0; e < 8; ++e) {
        int c = c0 + e;
        float v = (c < kC1Out) ? w2[(size_t)row * kC1Out + c] : 0.f;
        unsigned short h = f2bf(v);
        float rem = v - bf2f(h);
        hi[e] = (short)h;
        lo[e] = (short)f2bf(rem);
    }
    w2t_hi[idx] = hi;
    w2t_lo[idx] = lo;
}

// ---------------- K1: feat[p][c] -------------------------------------------
__global__ void k_feat(const float* __restrict__ x, float* __restrict__ feat) {
    int c = blockIdx.x * 256 + threadIdx.x;
    int p = blockIdx.y;
    if (c >= kC1In) return;
    int b = p >> 10, i = (p >> 5) & 31, j = p & 31;
    int y0 = 2 * i - 3, x0 = 2 * j - 3;
    const float* xb = x + (size_t)b * kC * kH * kW;
    float m = -INFINITY;
    if (c < 196) {
        int g = c / 49, r = c % 49, a = r / 7, bk = r % 7;
        int yy = y0 + a, xx = x0 + bk;
        #pragma unroll
        for (int ch = 0; ch < 16; ++ch)
            m = fmaxf(m, xval(xb, g * 16 + ch, yy, xx));
    } else if (c < 644) {
        int c2 = c - 196;
        int g = c2 / 112, r = c2 % 112, ch = r / 7, bk = r % 7;
        int xx = x0 + bk, ca = g * 16 + ch;
        #pragma unroll
        for (int a = 0; a < 7; ++a)
            m = fmaxf(m, xval(xb, ca, y0 + a, xx));
    } else {
        int c3 = c - 644;
        int g = c3 / 112, r = c3 % 112, ch = r / 7, a = r % 7;
        int yy = y0 + a, ca = g * 16 + ch;
        #pragma unroll
        for (int bk = 0; bk < 7; ++bk)
            m = fmaxf(m, xval(xb, ca, yy, x0 + bk));
    }
    feat[(size_t)p * kC1In + c] = m;
}

// ---------------- K2: h = feat * w1^T (stride-320 out), fused BN sums ------
__global__ __launch_bounds__(256) void k_gemm1(const float* __restrict__ feat,
        const float* __restrict__ w1, float* __restrict__ h,
        float* __restrict__ sum_, float* __restrict__ sumsq_) {
    __shared__ float As[16][65];
    __shared__ float Bs[16][65];
    __shared__ float lsum[64], lsq[64];
    int tid = threadIdx.x;
    int tx = tid & 15, ty = tid >> 4;
    int row0 = blockIdx.y * 64, col0 = blockIdx.x * 64;
    float acc[4][4] = {};
    for (int k0 = 0; k0 < kC1In; k0 += 16) {
        #pragma unroll
        for (int l = 0; l < 4; ++l) {
            int idx = tid + l * 256;
            int m = idx >> 4, k = idx & 15;
            bool kin = (k0 + k < kC1In);
            As[k][m] = kin ? feat[(size_t)(row0 + m) * kC1In + k0 + k] : 0.f;
            float bv = 0.f;
            if (kin && (col0 + m < kC1Out))
                bv = w1[(size_t)(col0 + m) * kC1In + k0 + k];
            Bs[k][m] = bv;
        }
        __syncthreads();
        #pragma unroll
        for (int k = 0; k < 16; ++k) {
            float a[4], bvv[4];
            #pragma unroll
            for (int i = 0; i < 4; ++i) a[i] = As[k][ty + 16 * i];
            #pragma unroll
            for (int j = 0; j < 4; ++j) bvv[j] = Bs[k][tx + 16 * j];
            #pragma unroll
            for (int i = 0; i < 4; ++i)
                #pragma unroll
                for (int j = 0; j < 4; ++j)
                    acc[i][j] += a[i] * bvv[j];
        }
        __syncthreads();
    }
    if (tid < 64) { lsum[tid] = 0.f; lsq[tid] = 0.f; }
    __syncthreads();
    #pragma unroll
    for (int i = 0; i < 4; ++i) {
        int m = ty + 16 * i;
        #pragma unroll
        for (int j = 0; j < 4; ++j) {
            int n = tx + 16 * j;
            float v = acc[i][j];
            h[(size_t)(row0 + m) * kC1P + col0 + n] = v;   // padded cols are 0 (Bs zero-filled)
            if (col0 + n < kC1Out) {
                atomicAdd(&lsum[n], v);
                atomicAdd(&lsq[n], v * v);
            }
        }
    }
    __syncthreads();
    if (tid < 64 && col0 + tid < kC1Out) {
        atomicAdd(&sum_[col0 + tid], lsum[tid]);
        atomicAdd(&sumsq_[col0 + tid], lsq[tid]);
    }
}

// ---------------- K3: finalize BN scale/shift ------------------------------
__global__ void k_finalize(const float* __restrict__ sum_, const float* __restrict__ sumsq_,
                           const float* __restrict__ gamma, const float* __restrict__ beta,
                           float* __restrict__ scale, float* __restrict__ shift) {
    int o = blockIdx.x * 256 + threadIdx.x;
    if (o >= kC1Out) return;
    float mu  = sum_[o]   * (1.f / kNP);
    float var = sumsq_[o] * (1.f / kNP) - mu * mu;
    float sc  = gamma[o] * rsqrtf(var + 1e-5f);
    scale[o] = sc;
    shift[o] = beta[o] - mu * sc;
}

// ---------------- K4a: BN+ReLU h -> frag-ready bf16 hi/lo ------------------
// layout: ht[((ptile*10 + t)*64 + lane)] = 8 bf16; value[e] =
//   relu(bn(h[(ptile*16 + (lane&15)) * 320 + t*32 + (lane>>4)*8 + e]))
__global__ void k_split_h(const float* __restrict__ h,
                          const float* __restrict__ scale, const float* __restrict__ shift,
                          bf16x8* __restrict__ ht_hi, bf16x8* __restrict__ ht_lo) {
    int idx = blockIdx.x * 256 + threadIdx.x;   // 512*10*64 = 327680
    int lane = idx & 63;
    int t = (idx >> 6) % 10;
    int ptile = idx / 640;
    int pos = ptile * 16 + (lane & 15);
    int c0 = t * 32 + ((lane >> 4) << 3);
    float vv[8];
    *(float4*)&vv[0] = *(const float4*)(h + (size_t)pos * kC1P + c0);
    *(float4*)&vv[4] = *(const float4*)(h + (size_t)pos * kC1P + c0 + 4);
    bf16x8 hi, lo;
    #pragma unroll
    for (int e = 0; e < 8; ++e) {
        int c = c0 + e;
        float v = (c < kC1Out) ? fmaxf(vv[e] * scale[c] + shift[c], 0.f) : 0.f;
        unsigned short hb = f2bf(v);
        float rem = v - bf2f(hb);
        hi[e] = (short)hb;
        lo[e] = (short)f2bf(rem);
    }
    ht_hi[idx] = hi;
    ht_lo[idx] = lo;
}

// ---------------- K4b: MFMA GEMM2 -> softmax(49) -> fp32 patch sum ---------
// block: 16 positions (ptile) x one group g. 256 threads = 4 waves.
// wave w computes slots k = w, w+4, ... (each slot = one 16x16 MFMA tile,
// M=16 pos, N=16 n, K=320 over 10 steps, 3 MFMAs/step split-precision).
__global__ __launch_bounds__(256) void k_fused(
        const bf16x8* __restrict__ ht_hi, const bf16x8* __restrict__ ht_lo,
        const bf16x8* __restrict__ w2t_hi, const bf16x8* __restrict__ w2t_lo,
        const float* __restrict__ b2, const float* __restrict__ x,
        float* __restrict__ out) {
    __shared__ float wt[16 * kWtStride];   // 50.4 KB
    int tid = threadIdx.x;
    int lane = tid & 63, wv = tid >> 6;
    int bid = blockIdx.x;
    int g = bid >> 9, ptile = bid & 511;

    // A fragments (hi/lo), resident for all slots
    bf16x8 ahi[10], alo[10];
    {
        const bf16x8* hb = ht_hi + (size_t)ptile * 640 + lane;
        const bf16x8* lb = ht_lo + (size_t)ptile * 640 + lane;
        #pragma unroll
        for (int t = 0; t < 10; ++t) { ahi[t] = hb[t * 64]; alo[t] = lb[t * 64]; }
    }

    int col = lane & 15, rgrp = lane >> 4;
    for (int k = wv; k < 49; k += 4) {
        f32x4 acc = {0.f, 0.f, 0.f, 0.f};
        const bf16x8* wb = w2t_hi + ((size_t)(g * 49 + k) * 10) * 64 + lane;
        const bf16x8* wl = w2t_lo + ((size_t)(g * 49 + k) * 10) * 64 + lane;
        #pragma unroll
        for (int t = 0; t < 10; ++t) {
            bf16x8 bh = wb[t * 64];
            bf16x8 bl = wl[t * 64];
            acc = __builtin_amdgcn_mfma_f32_16x16x32_bf16(ahi[t], bh, acc, 0, 0, 0);
            acc = __builtin_amdgcn_mfma_f32_16x16x32_bf16(ahi[t], bl, acc, 0, 0, 0);
            acc = __builtin_amdgcn_mfma_f32_16x16x32_bf16(alo[t], bh, acc, 0, 0, 0);
        }
        float bias = b2[g * 784 + k * 16 + col];
        #pragma unroll
        for (int r = 0; r < 4; ++r) {
            int pos = rgrp * 4 + r;                       // C: row=(lane>>4)*4+reg
            wt[pos * kWtStride + k * 16 + col] = acc[r] + bias;
        }
    }
    __syncthreads();

    // softmax over k per (pos, n), fold /49 into weights
    {
        int pos = tid >> 4, n = tid & 15;
        float* base = wt + pos * kWtStride + n;
        float m = -INFINITY;
        #pragma unroll
        for (int k = 0; k < 49; ++k) m = fmaxf(m, base[k * 16]);
        float s = 0.f;
        #pragma unroll
        for (int k = 0; k < 49; ++k) s += __expf(base[k * 16] - m);
        float inv = 1.f / (s * 49.f);
        #pragma unroll
        for (int k = 0; k < 49; ++k) base[k * 16] = __expf(base[k * 16] - m) * inv;
    }
    __syncthreads();

    // phase 4: out[g*16+c16][pos][n] = sum_k patch * wt  (exact fp32)
    {
        int pos = tid & 15, c16 = tid >> 4;
        int p = ptile * 16 + pos;
        int b = p >> 10, i = (p >> 5) & 31, j = p & 31;
        int y0 = 2 * i - 3, x0c = 2 * j - 3;
        const float* xc = x + (((size_t)b * 64 + g * 16 + c16) << 12);
        float patch[49];
        #pragma unroll
        for (int a = 0; a < 7; ++a) {
            int yy = y0 + a;
            #pragma unroll
            for (int bk = 0; bk < 7; ++bk) {
                int xx = x0c + bk;
                patch[a * 7 + bk] = ((unsigned)yy < 64u && (unsigned)xx < 64u)
                                  ? xc[(yy << 6) + xx] : 0.f;
            }
        }
        float o[16] = {};
        const f32x4* wrow = (const f32x4*)(wt + pos * kWtStride);
        #pragma unroll
        for (int k = 0; k < 49; ++k) {
            float pk = patch[k];
            #pragma unroll
            for (int q = 0; q < 4; ++q) {
                f32x4 w4 = wrow[k * 4 + q];
                o[q * 4 + 0] += pk * w4[0];
                o[q * 4 + 1] += pk * w4[1];
                o[q * 4 + 2] += pk * w4[2];
                o[q * 4 + 3] += pk * w4[3];
            }
        }
        float* outb = out + (((size_t)b * 64 + g * 16 + c16) << 14);
        #pragma unroll
        for (int n1 = 0; n1 < 4; ++n1) {
            f32x4 st = { o[n1 * 4 + 0], o[n1 * 4 + 1], o[n1 * 4 + 2], o[n1 * 4 + 3] };
            *(f32x4*)(outb + (i * 4 + n1) * 128 + j * 4) = st;
        }
    }
}

extern "C" void kernel_launch(void* const* d_in, const int* in_sizes, int n_in,
                              void* d_out, int out_size, void* d_ws, size_t ws_size,
                              hipStream_t stream) {
    const float* x     = (const float*)d_in[0];
    const float* w1    = (const float*)d_in[1];
    const float* gamma = (const float*)d_in[2];
    const float* beta  = (const float*)d_in[3];
    const float* w2    = (const float*)d_in[4];
    const float* b2    = (const float*)d_in[5];
    float* out = (float*)d_out;

    // workspace layout (float units), ~50.3 MB total
    float* ws     = (float*)d_ws;
    float* feat   = ws;                                   // 8192*1092 = 8,945,664
    float* h      = feat + (size_t)kNP * kC1In;           // 8192*320  = 2,621,440
    float* w2thi_f= h + (size_t)kNP * kC1P;               // 501,760
    float* w2tlo_f= w2thi_f + 501760;                     // 501,760
    float* sum_   = w2tlo_f + 501760;
    float* sumsq_ = sum_ + 320;
    float* scale  = sumsq_ + 320;
    float* shift  = scale + 320;

    // ht_hi/ht_lo reuse feat's space (feat is dead after k_gemm1)
    bf16x8* ht_hi = (bf16x8*)feat;                        // 327,680 * 16B = 5.24 MB
    bf16x8* ht_lo = (bf16x8*)(feat + 1310720);
    bf16x8* w2t_hi = (bf16x8*)w2thi_f;
    bf16x8* w2t_lo = (bf16x8*)w2tlo_f;

    hipMemsetAsync(sum_, 0, 2 * 320 * sizeof(float), stream);
    k_w2split<<<490, 256, 0, stream>>>(w2, w2t_hi, w2t_lo);
    k_feat<<<dim3(5, kNP), 256, 0, stream>>>(x, feat);
    k_gemm1<<<dim3(5, kNP / 64), 256, 0, stream>>>(feat, w1, h, sum_, sumsq_);
    k_finalize<<<2, 256, 0, stream>>>(sum_, sumsq_, gamma, beta, scale, shift);
    k_split_h<<<1280, 256, 0, stream>>>(h, scale, shift, ht_hi, ht_lo);
    k_fused<<<kG * (kNP / 16), 256, 0, stream>>>(ht_hi, ht_lo, w2t_hi, w2t_lo, b2, x, out);
}

// Round 3
// 241.796 us; speedup vs baseline: 7.2772x; 1.9684x over previous
//
#include <hip/hip_runtime.h>

namespace {
constexpr int kB    = 8;
constexpr int kC    = 64;
constexpr int kH    = 64, kW = 64;
constexpr int kNP   = 8192;             // positions
constexpr int kC1In = 1092;
constexpr int kKP   = 1152;             // padded K for GEMM1 (18 x 64)
constexpr int kC1Out= 313;
constexpr int kC2Out= 3136;
constexpr int kC1P  = 320;              // padded C1Out
constexpr int kWtStride = 788;          // LDS wt row stride (floats)
}

typedef __attribute__((ext_vector_type(8))) short bf16x8;
typedef __attribute__((ext_vector_type(4))) float f32x4;

__device__ __forceinline__ unsigned short f2bf(float f) {
    unsigned u = __float_as_uint(f);
    unsigned r = (u + 0x7fffu + ((u >> 16) & 1u)) >> 16;   // RNE
    return (unsigned short)r;
}
__device__ __forceinline__ float bf2f(unsigned short h) {
    return __uint_as_float(((unsigned)h) << 16);
}

__device__ __forceinline__ float xval(const float* __restrict__ xb, int ch, int yy, int xx) {
    if ((unsigned)yy < 64u && (unsigned)xx < 64u)
        return xb[((size_t)ch << 12) + (yy << 6) + xx];
    return 0.f;
}

// ---------------- K0: split w2 into frag-ready bf16 hi/lo -------------------
__global__ void k_w2split(const float* __restrict__ w2,
                          bf16x8* __restrict__ w2t_hi, bf16x8* __restrict__ w2t_lo) {
    int idx = blockIdx.x * 256 + threadIdx.x;   // 4*49*10*64 = 125440
    int lane = idx & 63;
    int t = (idx >> 6) % 10;
    int k = (idx / 640) % 49;
    int g = idx / 31360;
    int n = lane & 15, c0 = t * 32 + ((lane >> 4) << 3);
    int row = g * 784 + k * 16 + n;
    bf16x8 hi, lo;
    #pragma unroll
    for (int e = 0; e < 8; ++e) {
        int c = c0 + e;
        float v = (c < kC1Out) ? w2[(size_t)row * kC1Out + c] : 0.f;
        unsigned short h = f2bf(v);
        float rem = v - bf2f(h);
        hi[e] = (short)h;
        lo[e] = (short)f2bf(rem);
    }
    w2t_hi[idx] = hi;
    w2t_lo[idx] = lo;
}

// ---------------- K0b: w1 [313][1092] -> bf16 [320][1152] ------------------
__global__ void k_w1cvt(const float* __restrict__ w1, unsigned short* __restrict__ w1s) {
    int idx = blockIdx.x * 256 + threadIdx.x;   // 320*1152 = 368640
    if (idx >= kC1P * kKP) return;
    int r = idx / kKP, c = idx - r * kKP;
    float v = (r < kC1Out && c < kC1In) ? w1[(size_t)r * kC1In + c] : 0.f;
    w1s[idx] = f2bf(v);
}

// ---------------- K1: feat[p][c] in bf16, K padded to 1152 -----------------
__global__ void k_feat(const float* __restrict__ x, unsigned short* __restrict__ feat_bf) {
    int c = blockIdx.x * 256 + threadIdx.x;
    int p = blockIdx.y;
    if (c >= kKP) return;
    unsigned short o = 0;
    if (c < kC1In) {
        int b = p >> 10, i = (p >> 5) & 31, j = p & 31;
        int y0 = 2 * i - 3, x0 = 2 * j - 3;
        const float* xb = x + (size_t)b * kC * kH * kW;
        float m = -INFINITY;
        if (c < 196) {
            int g = c / 49, r = c % 49, a = r / 7, bk = r % 7;
            int yy = y0 + a, xx = x0 + bk;
            #pragma unroll
            for (int ch = 0; ch < 16; ++ch)
                m = fmaxf(m, xval(xb, g * 16 + ch, yy, xx));
        } else if (c < 644) {
            int c2 = c - 196;
            int g = c2 / 112, r = c2 % 112, ch = r / 7, bk = r % 7;
            int xx = x0 + bk, ca = g * 16 + ch;
            #pragma unroll
            for (int a = 0; a < 7; ++a)
                m = fmaxf(m, xval(xb, ca, y0 + a, xx));
        } else {
            int c3 = c - 644;
            int g = c3 / 112, r = c3 % 112, ch = r / 7, a = r % 7;
            int yy = y0 + a, ca = g * 16 + ch;
            #pragma unroll
            for (int bk = 0; bk < 7; ++bk)
                m = fmaxf(m, xval(xb, ca, yy, x0 + bk));
        }
        o = f2bf(m);
    }
    feat_bf[(size_t)p * kKP + c] = o;
}

// ---------------- K2: MFMA GEMM1: h = feat * w1s^T, fused BN sums ----------
// 64x64 tile, BK=64, 4 waves as 2x2, each wave 2x2 of 16x16x32 MFMA tiles.
// LDS: linear dest for global_load_lds; source octet pre-swizzled by row&7,
// reads use the same XOR (rule #21 both-sides swizzle).
__global__ __launch_bounds__(256) void k_gemm1(
        const unsigned short* __restrict__ feat_bf, const unsigned short* __restrict__ w1s,
        float* __restrict__ h, float* __restrict__ sum_, float* __restrict__ sumsq_) {
    __shared__ unsigned short Ald[64 * 64];   // [row][oct(swz)] 8KB
    __shared__ unsigned short Bld[64 * 64];   // 8KB
    __shared__ float lsum[64], lsq[64];
    int tid = threadIdx.x;
    int lane = tid & 63, wv = tid >> 6;
    int row0 = blockIdx.y * 64, col0 = blockIdx.x * 64;
    int wr = wv >> 1, wc = wv & 1;
    int srow = lane >> 3;                       // 0..7
    int soct = (lane & 7) ^ srow;               // swizzled source octet
    int frow = lane & 15, fk = lane >> 4;       // frag row / oct-group

    f32x4 acc[2][2] = {};
    for (int k0 = 0; k0 < kKP; k0 += 64) {
        // stage 16 chunks (8 A + 8 B), 4 per wave, 16B/lane each
        #pragma unroll
        for (int qq = 0; qq < 4; ++qq) {
            int q = wv + qq * 4;
            const unsigned short* srcbase;
            unsigned short* dst;
            int grow;
            if (q < 8) { grow = row0 + q * 8 + srow; srcbase = feat_bf; dst = Ald + q * 512; }
            else       { grow = col0 + (q - 8) * 8 + srow; srcbase = w1s; dst = Bld + (q - 8) * 512; }
            const unsigned short* src = srcbase + (size_t)grow * kKP + k0 + soct * 8;
            __builtin_amdgcn_global_load_lds(
                (const __attribute__((address_space(1))) unsigned int*)src,
                (__attribute__((address_space(3))) unsigned int*)dst, 16, 0, 0);
        }
        __syncthreads();
        #pragma unroll
        for (int ks = 0; ks < 2; ++ks) {
            int oct = ks * 4 + fk;
            bf16x8 a0, a1, b0, b1;
            { int r = wr * 32 + frow;      a0 = *(const bf16x8*)(Ald + (r * 8 + (oct ^ (r & 7))) * 8); }
            { int r = wr * 32 + 16 + frow; a1 = *(const bf16x8*)(Ald + (r * 8 + (oct ^ (r & 7))) * 8); }
            { int r = wc * 32 + frow;      b0 = *(const bf16x8*)(Bld + (r * 8 + (oct ^ (r & 7))) * 8); }
            { int r = wc * 32 + 16 + frow; b1 = *(const bf16x8*)(Bld + (r * 8 + (oct ^ (r & 7))) * 8); }
            acc[0][0] = __builtin_amdgcn_mfma_f32_16x16x32_bf16(a0, b0, acc[0][0], 0, 0, 0);
            acc[0][1] = __builtin_amdgcn_mfma_f32_16x16x32_bf16(a0, b1, acc[0][1], 0, 0, 0);
            acc[1][0] = __builtin_amdgcn_mfma_f32_16x16x32_bf16(a1, b0, acc[1][0], 0, 0, 0);
            acc[1][1] = __builtin_amdgcn_mfma_f32_16x16x32_bf16(a1, b1, acc[1][1], 0, 0, 0);
        }
        __syncthreads();
    }

    if (tid < 64) { lsum[tid] = 0.f; lsq[tid] = 0.f; }
    __syncthreads();
    #pragma unroll
    for (int i = 0; i < 2; ++i) {
        int mrow = row0 + wr * 32 + i * 16 + (lane >> 4) * 4;
        #pragma unroll
        for (int j = 0; j < 2; ++j) {
            int col_l = wc * 32 + j * 16 + (lane & 15);
            float s = 0.f, sq = 0.f;
            #pragma unroll
            for (int r = 0; r < 4; ++r) {
                float v = acc[i][j][r];
                h[(size_t)(mrow + r) * kC1P + col0 + col_l] = v;
                s += v; sq += v * v;
            }
            atomicAdd(&lsum[col_l], s);
            atomicAdd(&lsq[col_l], sq);
        }
    }
    __syncthreads();
    if (tid < 64 && col0 + tid < kC1Out) {
        atomicAdd(&sum_[col0 + tid], lsum[tid]);
        atomicAdd(&sumsq_[col0 + tid], lsq[tid]);
    }
}

// ---------------- K3: finalize BN scale/shift ------------------------------
__global__ void k_finalize(const float* __restrict__ sum_, const float* __restrict__ sumsq_,
                           const float* __restrict__ gamma, const float* __restrict__ beta,
                           float* __restrict__ scale, float* __restrict__ shift) {
    int o = blockIdx.x * 256 + threadIdx.x;
    if (o >= kC1Out) return;
    float mu  = sum_[o]   * (1.f / kNP);
    float var = sumsq_[o] * (1.f / kNP) - mu * mu;
    float sc  = gamma[o] * rsqrtf(var + 1e-5f);
    scale[o] = sc;
    shift[o] = beta[o] - mu * sc;
}

// ---------------- K4a: BN+ReLU h -> frag-ready bf16 hi/lo ------------------
__global__ void k_split_h(const float* __restrict__ h,
                          const float* __restrict__ scale, const float* __restrict__ shift,
                          bf16x8* __restrict__ ht_hi, bf16x8* __restrict__ ht_lo) {
    int idx = blockIdx.x * 256 + threadIdx.x;   // 512*10*64 = 327680
    int lane = idx & 63;
    int t = (idx >> 6) % 10;
    int ptile = idx / 640;
    int pos = ptile * 16 + (lane & 15);
    int c0 = t * 32 + ((lane >> 4) << 3);
    float vv[8];
    *(float4*)&vv[0] = *(const float4*)(h + (size_t)pos * kC1P + c0);
    *(float4*)&vv[4] = *(const float4*)(h + (size_t)pos * kC1P + c0 + 4);
    bf16x8 hi, lo;
    #pragma unroll
    for (int e = 0; e < 8; ++e) {
        int c = c0 + e;
        float v = (c < kC1Out) ? fmaxf(vv[e] * scale[c] + shift[c], 0.f) : 0.f;
        unsigned short hb = f2bf(v);
        float rem = v - bf2f(hb);
        hi[e] = (short)hb;
        lo[e] = (short)f2bf(rem);
    }
    ht_hi[idx] = hi;
    ht_lo[idx] = lo;
}

// ---------------- K4b: MFMA GEMM2 -> softmax(49) -> fp32 patch sum ---------
__global__ __launch_bounds__(256) void k_fused(
        const bf16x8* __restrict__ ht_hi, const bf16x8* __restrict__ ht_lo,
        const bf16x8* __restrict__ w2t_hi, const bf16x8* __restrict__ w2t_lo,
        const float* __restrict__ b2, const float* __restrict__ x,
        float* __restrict__ out) {
    __shared__ float wt[16 * kWtStride];   // 50.4 KB
    int tid = threadIdx.x;
    int lane = tid & 63, wv = tid >> 6;
    int bid = blockIdx.x;
    int g = bid >> 9, ptile = bid & 511;

    bf16x8 ahi[10], alo[10];
    {
        const bf16x8* hb = ht_hi + (size_t)ptile * 640 + lane;
        const bf16x8* lb = ht_lo + (size_t)ptile * 640 + lane;
        #pragma unroll
        for (int t = 0; t < 10; ++t) { ahi[t] = hb[t * 64]; alo[t] = lb[t * 64]; }
    }

    int col = lane & 15, rgrp = lane >> 4;
    for (int k = wv; k < 49; k += 4) {
        f32x4 acc = {0.f, 0.f, 0.f, 0.f};
        const bf16x8* wb = w2t_hi + ((size_t)(g * 49 + k) * 10) * 64 + lane;
        const bf16x8* wl = w2t_lo + ((size_t)(g * 49 + k) * 10) * 64 + lane;
        #pragma unroll
        for (int t = 0; t < 10; ++t) {
            bf16x8 bh = wb[t * 64];
            bf16x8 bl = wl[t * 64];
            acc = __builtin_amdgcn_mfma_f32_16x16x32_bf16(ahi[t], bh, acc, 0, 0, 0);
            acc = __builtin_amdgcn_mfma_f32_16x16x32_bf16(ahi[t], bl, acc, 0, 0, 0);
            acc = __builtin_amdgcn_mfma_f32_16x16x32_bf16(alo[t], bh, acc, 0, 0, 0);
        }
        float bias = b2[g * 784 + k * 16 + col];
        #pragma unroll
        for (int r = 0; r < 4; ++r) {
            int pos = rgrp * 4 + r;
            wt[pos * kWtStride + k * 16 + col] = acc[r] + bias;
        }
    }
    __syncthreads();

    {
        int pos = tid >> 4, n = tid & 15;
        float* base = wt + pos * kWtStride + n;
        float m = -INFINITY;
        #pragma unroll
        for (int k = 0; k < 49; ++k) m = fmaxf(m, base[k * 16]);
        float s = 0.f;
        #pragma unroll
        for (int k = 0; k < 49; ++k) s += __expf(base[k * 16] - m);
        float inv = 1.f / (s * 49.f);
        #pragma unroll
        for (int k = 0; k < 49; ++k) base[k * 16] = __expf(base[k * 16] - m) * inv;
    }
    __syncthreads();

    {
        int pos = tid & 15, c16 = tid >> 4;
        int p = ptile * 16 + pos;
        int b = p >> 10, i = (p >> 5) & 31, j = p & 31;
        int y0 = 2 * i - 3, x0c = 2 * j - 3;
        const float* xc = x + (((size_t)b * 64 + g * 16 + c16) << 12);
        float patch[49];
        #pragma unroll
        for (int a = 0; a < 7; ++a) {
            int yy = y0 + a;
            #pragma unroll
            for (int bk = 0; bk < 7; ++bk) {
                int xx = x0c + bk;
                patch[a * 7 + bk] = ((unsigned)yy < 64u && (unsigned)xx < 64u)
                                  ? xc[(yy << 6) + xx] : 0.f;
            }
        }
        float o[16] = {};
        const f32x4* wrow = (const f32x4*)(wt + pos * kWtStride);
        #pragma unroll
        for (int k = 0; k < 49; ++k) {
            float pk = patch[k];
            #pragma unroll
            for (int q = 0; q < 4; ++q) {
                f32x4 w4 = wrow[k * 4 + q];
                o[q * 4 + 0] += pk * w4[0];
                o[q * 4 + 1] += pk * w4[1];
                o[q * 4 + 2] += pk * w4[2];
                o[q * 4 + 3] += pk * w4[3];
            }
        }
        float* outb = out + (((size_t)b * 64 + g * 16 + c16) << 14);
        #pragma unroll
        for (int n1 = 0; n1 < 4; ++n1) {
            f32x4 st = { o[n1 * 4 + 0], o[n1 * 4 + 1], o[n1 * 4 + 2], o[n1 * 4 + 3] };
            *(f32x4*)(outb + (i * 4 + n1) * 128 + j * 4) = st;
        }
    }
}

extern "C" void kernel_launch(void* const* d_in, const int* in_sizes, int n_in,
                              void* d_out, int out_size, void* d_ws, size_t ws_size,
                              hipStream_t stream) {
    const float* x     = (const float*)d_in[0];
    const float* w1    = (const float*)d_in[1];
    const float* gamma = (const float*)d_in[2];
    const float* beta  = (const float*)d_in[3];
    const float* w2    = (const float*)d_in[4];
    const float* b2    = (const float*)d_in[5];
    float* out = (float*)d_out;

    // workspace layout (float units), ~34 MB total
    float* ws = (float*)d_ws;
    unsigned short* feat_bf = (unsigned short*)ws;        // 8192*1152 shorts = 4,718,592 fl
    float* h       = ws + 4718592;                        // 8192*320 = 2,621,440 fl
    float* w2thi_f = h + 2621440;                         // 501,760 fl
    float* w2tlo_f = w2thi_f + 501760;                    // 501,760 fl
    unsigned short* w1s = (unsigned short*)(w2tlo_f + 501760);  // 368,640 shorts = 184,320 fl
    float* sum_   = w2tlo_f + 501760 + 184320;
    float* sumsq_ = sum_ + 320;
    float* scale  = sumsq_ + 320;
    float* shift  = scale + 320;

    // ht reuses feat region (feat dead after k_gemm1)
    bf16x8* ht_hi = (bf16x8*)ws;                          // 5.24 MB
    bf16x8* ht_lo = (bf16x8*)(ws + 1310720);              // 5.24 MB
    bf16x8* w2t_hi = (bf16x8*)w2thi_f;
    bf16x8* w2t_lo = (bf16x8*)w2tlo_f;

    hipMemsetAsync(sum_, 0, 2 * 320 * sizeof(float), stream);
    k_w2split<<<490, 256, 0, stream>>>(w2, w2t_hi, w2t_lo);
    k_w1cvt<<<(kC1P * kKP + 255) / 256, 256, 0, stream>>>(w1, w1s);
    k_feat<<<dim3(5, kNP), 256, 0, stream>>>(x, feat_bf);
    k_gemm1<<<dim3(5, kNP / 64), 256, 0, stream>>>(feat_bf, w1s, h, sum_, sumsq_);
    k_finalize<<<2, 256, 0, stream>>>(sum_, sumsq_, gamma, beta, scale, shift);
    k_split_h<<<1280, 256, 0, stream>>>(h, scale, shift, ht_hi, ht_lo);
    k_fused<<<2048, 256, 0, stream>>>(ht_hi, ht_lo, w2t_hi, w2t_lo, b2, x, out);
}